// Round 1
// baseline (830.847 us; speedup 1.0000x reference)
//
#include <hip/hip_runtime.h>

#define T_STEPS 800
#define NBATCH  32
#define SSTATES 1024
#define ROW     5120   // SSTATES * 5

struct ScanSmem {
  float sbuf[2][ROW];      // staged score rows (double-buffered)
  float abuf[2][SSTATES];  // alpha/beta (double-buffered)
};

__device__ __forceinline__ float lse5(float v0, float v1, float v2, float v3, float v4) {
  float m = fmaxf(fmaxf(fmaxf(v0, v1), fmaxf(v2, v3)), v4);
  float s = __expf(v0 - m) + __expf(v1 - m) + __expf(v2 - m) +
            __expf(v3 - m) + __expf(v4 - m);
  return m + __logf(s);
}

// Raw barrier: LDS fence only, leaves vmcnt (global prefetch) in flight.
__device__ __forceinline__ void sync_lds() {
  asm volatile("s_waitcnt lgkmcnt(0)" ::: "memory");
  __builtin_amdgcn_s_barrier();
  asm volatile("" ::: "memory");
}

// DIR=0: forward scan (writes fwd rows into `out` = posts region).
// DIR=1: backward scan (writes bwd rows into `out` = bwd output).
// Both also write their half of the transposed scores copy (out0).
template <int DIR>
__device__ void scan_run(const float* __restrict__ scores, float* __restrict__ out,
                         float* __restrict__ out0, int n, ScanSmem& sm) {
  const int tid = threadIdx.x;
  const float* base = scores + (size_t)n * ROW;
  float* outn = out + (size_t)n * (T_STEPS + 1) * SSTATES;

  sm.abuf[0][tid] = 0.0f;
  float a = 0.0f;  // this thread's own alpha/beta (self-edge)
  if (DIR == 0) outn[tid] = 0.0f;                                   // fwd[0] = 0
  else          outn[(size_t)T_STEPS * SSTATES + tid] = 0.0f;       // bwd[T] = 0

  // per-thread gather constants
  const int sc0 = 5 * tid;
  int q, sc1;
  if (DIR == 0) {
    q = tid >> 2;           // alpha offsets: q, q+256, q+512, q+768 (broadcast x4 lanes)
    sc1 = 0;
  } else {
    const int j = tid >> 8;
    q = tid & 255;          // beta gather: float4 at abuf[4q..4q+3]
    sc1 = 20 * q + 1 + j;   // score positions sc1 + {0,5,10,15}
  }

  // 4-deep register prefetch (rows step..step+3), coalesced loads
  float r[4][5];
#pragma unroll
  for (int i = 0; i < 4; ++i) {
    const int t = DIR ? (T_STEPS - 1 - i) : i;
    const float* rp = base + (size_t)t * (NBATCH * ROW);
#pragma unroll
    for (int k = 0; k < 5; ++k) r[i][k] = rp[tid + k * SSTATES];
  }

  for (int p = 0; p < T_STEPS; p += 4) {
#pragma unroll
    for (int i = 0; i < 4; ++i) {
      const int step = p + i;
      const int t = DIR ? (T_STEPS - 1 - step) : step;
      const int cur = i & 1;  // step parity (p % 4 == 0)

      // stage current row regs -> LDS
#pragma unroll
      for (int k = 0; k < 5; ++k) sm.sbuf[cur][tid + k * SSTATES] = r[i][k];

      // fused transpose-copy: fwd handles t<400, bwd handles t>=400
      if (step < 400) {
        float* o0 = out0 + ((size_t)n * T_STEPS + t) * ROW;
#pragma unroll
        for (int k = 0; k < 5; ++k) o0[tid + k * SSTATES] = r[i][k];
      }

      sync_lds();

      // prefetch row step+4 into this slot (consumed next macro-iteration)
      if (step + 4 < T_STEPS) {
        const int tn = DIR ? (T_STEPS - 1 - (step + 4)) : (step + 4);
        const float* rp = base + (size_t)tn * (NBATCH * ROW);
#pragma unroll
        for (int k = 0; k < 5; ++k) r[i][k] = rp[tid + k * SSTATES];
      }

      float na;
      if (DIR == 0) {
        const float v0 = sm.sbuf[cur][sc0 + 0] + a;
        const float v1 = sm.sbuf[cur][sc0 + 1] + sm.abuf[cur][q];
        const float v2 = sm.sbuf[cur][sc0 + 2] + sm.abuf[cur][q + 256];
        const float v3 = sm.sbuf[cur][sc0 + 3] + sm.abuf[cur][q + 512];
        const float v4 = sm.sbuf[cur][sc0 + 4] + sm.abuf[cur][q + 768];
        na = lse5(v0, v1, v2, v3, v4);
      } else {
        const float4 av = *(const float4*)&sm.abuf[cur][4 * q];
        const float v0 = sm.sbuf[cur][sc0]      + a;
        const float v1 = sm.sbuf[cur][sc1 + 0]  + av.x;
        const float v2 = sm.sbuf[cur][sc1 + 5]  + av.y;
        const float v3 = sm.sbuf[cur][sc1 + 10] + av.z;
        const float v4 = sm.sbuf[cur][sc1 + 15] + av.w;
        na = lse5(v0, v1, v2, v3, v4);
      }

      const size_t t_out = DIR ? (size_t)t : (size_t)(step + 1);
      outn[t_out * SSTATES + tid] = na;
      a = na;
      sm.abuf[cur ^ 1][tid] = na;
    }
  }
}

__global__ __launch_bounds__(1024) void fused_scan(const float* __restrict__ scores,
                                                   float* __restrict__ out0,
                                                   float* __restrict__ bwdo,
                                                   float* __restrict__ fposts) {
  __shared__ ScanSmem sm;
  const int b = blockIdx.x;
  if (b < NBATCH) scan_run<0>(scores, fposts, out0, b, sm);
  else            scan_run<1>(scores, bwdo,   out0, b - NBATCH, sm);
}

// One wave per row of 1024: posts = softmax(fwd + bwd), in place over the fwd buffer.
__global__ __launch_bounds__(256) void posts_kernel(float* __restrict__ fp,
                                                    const float* __restrict__ bp) {
  const int lane = threadIdx.x & 63;
  const int wid  = threadIdx.x >> 6;
  const size_t row = (size_t)blockIdx.x * 4 + wid;
  float* f = fp + row * SSTATES;
  const float* b = bp + row * SSTATES;

  float x[16];
#pragma unroll
  for (int k = 0; k < 4; ++k) {
    const float4 fv = ((const float4*)f)[lane + 64 * k];
    const float4 bv = ((const float4*)b)[lane + 64 * k];
    x[4 * k + 0] = fv.x + bv.x;
    x[4 * k + 1] = fv.y + bv.y;
    x[4 * k + 2] = fv.z + bv.z;
    x[4 * k + 3] = fv.w + bv.w;
  }
  float m = x[0];
#pragma unroll
  for (int j = 1; j < 16; ++j) m = fmaxf(m, x[j]);
#pragma unroll
  for (int off = 32; off >= 1; off >>= 1) m = fmaxf(m, __shfl_xor(m, off));
  float ssum = 0.0f;
#pragma unroll
  for (int j = 0; j < 16; ++j) { x[j] = __expf(x[j] - m); ssum += x[j]; }
#pragma unroll
  for (int off = 32; off >= 1; off >>= 1) ssum += __shfl_xor(ssum, off);
  const float inv = 1.0f / ssum;
#pragma unroll
  for (int k = 0; k < 4; ++k) {
    float4 o;
    o.x = x[4 * k + 0] * inv;
    o.y = x[4 * k + 1] * inv;
    o.z = x[4 * k + 2] * inv;
    o.w = x[4 * k + 3] * inv;
    ((float4*)f)[lane + 64 * k] = o;
  }
}

extern "C" void kernel_launch(void* const* d_in, const int* in_sizes, int n_in,
                              void* d_out, int out_size, void* d_ws, size_t ws_size,
                              hipStream_t stream) {
  (void)in_sizes; (void)n_in; (void)d_ws; (void)ws_size; (void)out_size;
  const float* scores = (const float*)d_in[0];
  float* out = (float*)d_out;
  float* out0   = out;                                                  // (32,800,5120)
  float* bwdo   = out + (size_t)NBATCH * T_STEPS * ROW;                 // (32,801,1024)
  float* fposts = bwdo + (size_t)NBATCH * (T_STEPS + 1) * SSTATES;      // (32,801,1024)

  fused_scan<<<64, 1024, 0, stream>>>(scores, out0, bwdo, fposts);
  posts_kernel<<<(NBATCH * (T_STEPS + 1)) / 4, 256, 0, stream>>>(fposts, bwdo);
}